// Round 7
// baseline (127.885 us; speedup 1.0000x reference)
//
#include <hip/hip_runtime.h>
#include <math.h>

// HSTU jagged attention, MFMA bf16, dynamic-queue persistent blocks.
// out = (silu(Q K^T) / N * mask) V, no softmax. H=8, D=DV=64, N=1024.
// Mask (exact algebraic collapse of the reference):
//   valid(n,m) = (m < thr(n)) | (m == n),  thr(n) = (an>0 ? an : M) + c - 1,
//   an = clamp(n-c+1, 0, M), M = L-c+1-ncand; plus n<L (m<L implied).
// Work queue: items (ord,b,h), ord 0 -> qt=0 (cost nq), ord k -> qt=16-k
// (cost qt+1): descending cost => greedy LPT balancing across 1024 blocks.

#define HH     8
#define DDIM   64
#define QT     64
#define KT     64
#define STRIDE 512
#define NMAX   1024
#define NORD   16

typedef __attribute__((ext_vector_type(8))) short short8;
typedef __attribute__((ext_vector_type(4))) float f32x4;

// packed fp32x2 -> bf16x2 (RNE) via hardware v_cvt_pk_bf16_f32 (no builtin on gfx950)
static __device__ __forceinline__ uint pk2(float a, float b) {
  uint r;
  asm("v_cvt_pk_bf16_f32 %0, %1, %2" : "=v"(r) : "v"(a), "v"(b));
  return r;
}

// ---- pre-pass 1: K fp32 -> bf16 row-major; also zeroes the queue counter ----
__global__ void conv_k(const float* __restrict__ in, ushort* __restrict__ outp,
                       int n8, uint* __restrict__ ctr) {
  if (blockIdx.x == 0 && threadIdx.x == 0) *ctr = 0u;
  int i = blockIdx.x * blockDim.x + threadIdx.x;
  const int gs = gridDim.x * blockDim.x;
  for (; i < n8; i += gs) {
    const float4* p = (const float4*)(in + (size_t)i * 8);
    float4 a = p[0], b = p[1];
    uint4 o;
    o.x = pk2(a.x, a.y); o.y = pk2(a.z, a.w);
    o.z = pk2(b.x, b.y); o.w = pk2(b.z, b.w);
    *(uint4*)(outp + (size_t)i * 8) = o;
  }
}

// ---- pre-pass 2: V fp32 -> bf16 transposed, vt[(h*64+dv)][b*1024+m] ----
__global__ void conv_vT(const float* __restrict__ tv, ushort* __restrict__ vt,
                        const int* __restrict__ offsets, int Bb) {
  const int m0 = blockIdx.x * 64;
  const int h  = blockIdx.y;
  const int b  = blockIdx.z;
  const int off = offsets[b];
  const int L   = offsets[b + 1] - off;
  if (m0 >= L) return;
  __shared__ ushort tile[64][66];
  const int tid = threadIdx.x;
  const int r = tid >> 4, cc = (tid & 15) * 4;
#pragma unroll
  for (int ps = 0; ps < 4; ++ps) {
    int row = r + ps * 16;
    int t = off + min(m0 + row, L - 1);
    float4 v = *(const float4*)(tv + (size_t)t * STRIDE + h * DDIM + cc);
    *(uint*)&tile[row][cc]     = pk2(v.x, v.y);
    *(uint*)&tile[row][cc + 2] = pk2(v.z, v.w);
  }
  __syncthreads();
  const int dv = tid >> 2;
  const int tc = (tid & 3) * 16;
  const int VTROW = Bb * NMAX;
  ushort* orow = vt + (size_t)(h * DDIM + dv) * VTROW + b * NMAX + m0 + tc;
  uint o[8];
#pragma unroll
  for (int j = 0; j < 8; ++j)
    o[j] = (uint)tile[tc + 2 * j][dv] | ((uint)tile[tc + 2 * j + 1][dv] << 16);
  uint4 q0 = make_uint4(o[0], o[1], o[2], o[3]);
  uint4 q1 = make_uint4(o[4], o[5], o[6], o[7]);
  *(uint4*)&orow[0] = q0;
  *(uint4*)&orow[8] = q1;
}

__global__ void zero_ctr(uint* ctr) { *ctr = 0u; }

template <bool PRE>
__launch_bounds__(256)
__global__ void hstu_q(const float* __restrict__ tq,
                       const float* __restrict__ tk,
                       const float* __restrict__ tv,
                       const ushort* __restrict__ kbf,
                       const ushort* __restrict__ vbfT,
                       const int* __restrict__ offsets,
                       const int* __restrict__ pN,
                       const int* __restrict__ ncand,
                       const int* __restrict__ nctx,
                       float* __restrict__ out,
                       uint* __restrict__ ctr,
                       int Tm1, int Bb) {
  const int bhc    = Bb * HH;
  const int nitems = NORD * bhc;
  const int VTROW  = Bb * NMAX;

  __shared__ ushort Ks[KT * DDIM];     // K[k][d], swizzled       8 KB
  __shared__ ushort Vt[DDIM * KT];     // V^T[dv][m], swizzled    8 KB
  __shared__ ushort QPs[QT * DDIM];    // Q[q][d] then P strips   8 KB
  __shared__ int s_item;

  const int tid  = threadIdx.x;
  const int w    = tid >> 6;
  const int lane = tid & 63;
  const int lo   = lane & 15;
  const int hi   = lane >> 4;

  const int qrow4 = tid >> 4;          // Q staging: 16 thr/row, float4
  const int qcol4 = (tid & 15) * 4;
  const int k_r   = tid >> 3;          // K/V bf16 staging: 8 thr/row, uint4
  const int k_c   = (tid & 7) * 8;     // halfword col / m-chunk

  const float invN = 1.0f / (float)pN[0];

  uint4  kpre[2], vpre[2];
  float4 kpf[4];
  float  vpf[16];
  ushort* Pw = &QPs[w * 1024];

  for (;;) {
    __syncthreads();                   // prev item's LDS readers done
    if (tid == 0) s_item = (int)atomicAdd(ctr, 1u);
    __syncthreads();
    const int item = s_item;
    if (item >= nitems) return;
    const int ord = item / bhc;
    const int rem = item - ord * bhc;
    const int b = rem >> 3, h = rem & 7;
    const int qt = (ord == 0) ? 0 : (NORD - ord);
    const int off = offsets[b];
    const int L   = offsets[b + 1] - off;
    const int n0  = qt * QT;
    if (n0 >= L) continue;

    const int c = nctx[b];
    const int M = L - c + 1 - ncand[b];
    const int m_hi  = (n0 < c) ? L : min(n0 + QT, L);
    const int niter = (m_hi + KT - 1) / KT;

    // ---- issue tile-0 K/V loads (latency hides under Q staging) ----
    if (PRE) {
#pragma unroll
      for (int i = 0; i < 2; ++i) {
        int r = min(off + k_r + i * 32, Tm1);
        kpre[i] = *(const uint4*)(kbf + (size_t)r * STRIDE + h * DDIM + k_c);
        vpre[i] = *(const uint4*)(vbfT + (size_t)(h * DDIM + k_r + i * 32) * VTROW
                                  + b * NMAX + k_c);
      }
    } else {
#pragma unroll
      for (int jj = 0; jj < 4; ++jj) {
        int r = min(off + qrow4 + jj * 16, Tm1);
        kpf[jj] = *(const float4*)(tk + (size_t)r * STRIDE + h * DDIM + qcol4);
      }
#pragma unroll
      for (int j = 0; j < 16; ++j) {
        int r = min(off + w * 16 + j, Tm1);
        vpf[j] = tv[(size_t)r * STRIDE + h * DDIM + lane];
      }
    }

    // ---- stage Q (fp32 -> bf16, swizzled), hoist A-frags ----
#pragma unroll
    for (int jj = 0; jj < 4; ++jj) {
      int row = qrow4 + jj * 16;
      int r   = min(off + n0 + row, Tm1);
      float4 v = *(const float4*)(tq + (size_t)r * STRIDE + h * DDIM + qcol4);
      uint2 pk;
      pk.x = pk2(v.x, v.y);
      pk.y = pk2(v.z, v.w);
      *(uint2*)&QPs[row * 64 + (qcol4 ^ ((row & 7) << 3))] = pk;
    }
    __syncthreads();
    short8 qf[2];
    {
      int qrow = w * 16 + lo;
#pragma unroll
      for (int ks = 0; ks < 2; ++ks)
        qf[ks] = *(const short8*)&QPs[qrow * 64 + ((ks * 32 + hi * 8) ^ ((qrow & 7) << 3))];
    }

    // per-row mask params: valid = nok & ((m < thr) | (m == n))
    int n_r[4], thr[4];
    bool nok[4];
#pragma unroll
    for (int r = 0; r < 4; ++r) {
      const int n  = n0 + w * 16 + hi * 4 + r;
      const int an = min(max(n - c + 1, 0), M);
      n_r[r] = n;
      thr[r] = (an > 0 ? an : M) + c - 1;
      nok[r] = n < L;
    }

    f32x4 oacc[4];
#pragma unroll
    for (int i = 0; i < 4; ++i) oacc[i] = (f32x4){0.f, 0.f, 0.f, 0.f};

    for (int t = 0; t < niter; ++t) {
      const int m0 = t * KT;
      __syncthreads();  // prior iter's LDS readers done (t=0: Q hoist drained)

      // ---- ds_write current K/V tile from prefetch regs ----
      if (PRE) {
#pragma unroll
        for (int i = 0; i < 2; ++i) {
          int row = k_r + i * 32;
          int sw  = k_c ^ ((row & 7) << 3);
          *(uint4*)&Ks[row * 64 + sw] = kpre[i];
          *(uint4*)&Vt[row * 64 + sw] = vpre[i];
        }
      } else {
#pragma unroll
        for (int jj = 0; jj < 4; ++jj) {
          int row = qrow4 + jj * 16;
          uint2 pk;
          pk.x = pk2(kpf[jj].x, kpf[jj].y);
          pk.y = pk2(kpf[jj].z, kpf[jj].w);
          *(uint2*)&Ks[row * 64 + (qcol4 ^ ((row & 7) << 3))] = pk;
        }
        uint bb[8];
#pragma unroll
        for (int j = 0; j < 8; ++j) bb[j] = pk2(vpf[2 * j], vpf[2 * j + 1]);
        uint4 p0 = make_uint4(bb[0], bb[1], bb[2], bb[3]);
        uint4 p1 = make_uint4(bb[4], bb[5], bb[6], bb[7]);
        int s = (lane & 7) << 3;
        *(uint4*)&Vt[lane * 64 + ((w * 16)     ^ s)] = p0;
        *(uint4*)&Vt[lane * 64 + ((w * 16 + 8) ^ s)] = p1;
      }

      // ---- issue next tile's loads ----
      if (t + 1 < niter) {
        const int mn = m0 + KT;
        if (PRE) {
#pragma unroll
          for (int i = 0; i < 2; ++i) {
            int r = min(off + mn + k_r + i * 32, Tm1);
            kpre[i] = *(const uint4*)(kbf + (size_t)r * STRIDE + h * DDIM + k_c);
            vpre[i] = *(const uint4*)(vbfT + (size_t)(h * DDIM + k_r + i * 32) * VTROW
                                      + b * NMAX + mn + k_c);
          }
        } else {
#pragma unroll
          for (int jj = 0; jj < 4; ++jj) {
            int r = min(off + mn + qrow4 + jj * 16, Tm1);
            kpf[jj] = *(const float4*)(tk + (size_t)r * STRIDE + h * DDIM + qcol4);
          }
#pragma unroll
          for (int j = 0; j < 16; ++j) {
            int r = min(off + mn + w * 16 + j, Tm1);
            vpf[j] = tv[(size_t)r * STRIDE + h * DDIM + lane];
          }
        }
      }
      __syncthreads();  // K/V tile visible

      // ---- S = Q K^T (8 MFMA) ----
      f32x4 sacc[4];
#pragma unroll
      for (int i = 0; i < 4; ++i) sacc[i] = (f32x4){0.f, 0.f, 0.f, 0.f};
#pragma unroll
      for (int kc = 0; kc < 4; ++kc) {
        int krw = kc * 16 + lo;
#pragma unroll
        for (int ks = 0; ks < 2; ++ks) {
          short8 kf = *(const short8*)&Ks[krw * 64 + ((ks * 32 + hi * 8) ^ ((krw & 7) << 3))];
          sacc[kc] = __builtin_amdgcn_mfma_f32_16x16x32_bf16(qf[ks], kf, sacc[kc], 0, 0, 0);
        }
      }

      // ---- mask + silu/N, P -> own wave's LDS strip ----
#pragma unroll
      for (int kc = 0; kc < 4; ++kc) {
        const int mm = m0 + kc * 16 + lo;
#pragma unroll
        for (int r = 0; r < 4; ++r) {
          const bool valid = nok[r] & ((mm < thr[r]) | (mm == n_r[r]));
          float s = valid ? sacc[kc][r] : 0.f;   // silu(0)=0
          float pp = s * invN * __builtin_amdgcn_rcpf(1.f + __expf(-s));
          const int col = kc * 16 + lo;
          const int ql  = hi * 4 + r;
          Pw[ql * 64 + (col ^ ((ql & 7) << 3))] = (ushort)(pk2(pp, pp) & 0xFFFFu);
        }
      }

      // ---- O += P V (8 MFMA); P round-trip is wave-private ----
#pragma unroll
      for (int mc = 0; mc < 2; ++mc) {
        short8 pf = *(const short8*)&Pw[lo * 64 + ((mc * 32 + hi * 8) ^ ((lo & 7) << 3))];
#pragma unroll
        for (int dvc = 0; dvc < 4; ++dvc) {
          int vrow = dvc * 16 + lo;
          short8 vf = *(const short8*)&Vt[vrow * 64 + ((mc * 32 + hi * 8) ^ ((vrow & 7) << 3))];
          oacc[dvc] = __builtin_amdgcn_mfma_f32_16x16x32_bf16(pf, vf, oacc[dvc], 0, 0, 0);
        }
      }
    }

    // ---- write out (fp32), C-frag layout ----
#pragma unroll
    for (int dvc = 0; dvc < 4; ++dvc) {
#pragma unroll
      for (int r = 0; r < 4; ++r) {
        int n = n0 + w * 16 + hi * 4 + r;
        if (n < L)
          out[(size_t)(off + n) * STRIDE + h * DDIM + dvc * 16 + lo] = oacc[dvc][r];
      }
    }
  }
}

extern "C" void kernel_launch(void* const* d_in, const int* in_sizes, int n_in,
                              void* d_out, int out_size, void* d_ws, size_t ws_size,
                              hipStream_t stream) {
  const float* tq      = (const float*)d_in[0];
  const float* tk      = (const float*)d_in[1];
  const float* tv      = (const float*)d_in[2];
  const int*   offsets = (const int*)d_in[3];
  const int*   pN      = (const int*)d_in[4];
  const int*   ncand   = (const int*)d_in[5];
  const int*   nctx    = (const int*)d_in[6];
  float*       out     = (float*)d_out;

  const int B = in_sizes[3] - 1;
  const int T = in_sizes[0] / STRIDE;

  uint*   ctr    = (uint*)d_ws;
  ushort* kbf    = (ushort*)((char*)d_ws + 16);
  size_t  kbytes = (size_t)T * STRIDE * 2;
  ushort* vbfT   = (ushort*)((char*)d_ws + 16 + kbytes);
  size_t  vbytes = (size_t)STRIDE * (size_t)B * NMAX * 2;
  const size_t need = 16 + kbytes + vbytes;

  dim3 block(256);
  const int nblocks = 1024;   // 4 blocks/CU; queue balances load

  if (ws_size >= need) {
    const int n8 = (T * STRIDE) / 8;
    int nb = (n8 + 255) / 256;
    if (nb > 2048) nb = 2048;
    conv_k<<<nb, 256, 0, stream>>>(tk, kbf, n8, ctr);
    dim3 tgrid(NMAX / 64, HH, B);
    conv_vT<<<tgrid, 256, 0, stream>>>(tv, vbfT, offsets, B);
    hstu_q<true><<<nblocks, block, 0, stream>>>(tq, tk, tv, kbf, vbfT, offsets,
                                                pN, ncand, nctx, out, ctr,
                                                T - 1, B);
  } else {
    zero_ctr<<<1, 1, 0, stream>>>(ctr);
    hstu_q<false><<<nblocks, block, 0, stream>>>(tq, tk, tv, nullptr, nullptr,
                                                 offsets, pN, ncand, nctx, out,
                                                 ctr, T - 1, B);
  }
}

// Round 8
// 126.802 us; speedup vs baseline: 1.0085x; 1.0085x over previous
//
#include <hip/hip_runtime.h>
#include <math.h>

// HSTU jagged attention, MFMA bf16, dynamic-queue persistent blocks.
// out = (silu(Q K^T) / N * mask) V, no softmax. H=8, D=DV=64, N=1024.
// Mask (exact algebraic collapse of the reference):
//   valid(n,m) = (m < thr(n)) | (m == n),  thr(n) = (an>0 ? an : M) + c - 1,
//   an = clamp(n-c+1, 0, M), M = L-c+1-ncand; plus n<L (m<L implied).
// Work queue: items (ord,b,h), ord 0 -> qt=0 (cost nq), ord k -> qt=16-k:
// descending cost => greedy LPT balancing across 1024 persistent blocks.
// R8: __launch_bounds__(256,4) pins VGPR<=128 (kills the scratch spills that
// produced 175MB excess WRITE_SIZE in R7); Q loaded direct to registers.

#define HH     8
#define DDIM   64
#define QT     64
#define KT     64
#define STRIDE 512
#define NMAX   1024
#define NORD   16

typedef __attribute__((ext_vector_type(8))) short short8;
typedef __attribute__((ext_vector_type(4))) float f32x4;
typedef __attribute__((ext_vector_type(4))) uint  u32x4;

// packed fp32x2 -> bf16x2 (RNE) via v_cvt_pk_bf16_f32 (no builtin on gfx950)
static __device__ __forceinline__ uint pk2(float a, float b) {
  uint r;
  asm("v_cvt_pk_bf16_f32 %0, %1, %2" : "=v"(r) : "v"(a), "v"(b));
  return r;
}

// ---- pre-pass 1: K fp32 -> bf16 row-major; also zeroes the queue counter ----
__global__ void conv_k(const float* __restrict__ in, ushort* __restrict__ outp,
                       int n8, uint* __restrict__ ctr) {
  if (blockIdx.x == 0 && threadIdx.x == 0) *ctr = 0u;
  int i = blockIdx.x * blockDim.x + threadIdx.x;
  const int gs = gridDim.x * blockDim.x;
  for (; i < n8; i += gs) {
    const float4* p = (const float4*)(in + (size_t)i * 8);
    float4 a = p[0], b = p[1];
    uint4 o;
    o.x = pk2(a.x, a.y); o.y = pk2(a.z, a.w);
    o.z = pk2(b.x, b.y); o.w = pk2(b.z, b.w);
    *(uint4*)(outp + (size_t)i * 8) = o;
  }
}

// ---- pre-pass 2: V fp32 -> bf16 transposed, vt[(h*64+dv)][b*1024+m] ----
__global__ void conv_vT(const float* __restrict__ tv, ushort* __restrict__ vt,
                        const int* __restrict__ offsets, int Bb) {
  const int m0 = blockIdx.x * 64;
  const int h  = blockIdx.y;
  const int b  = blockIdx.z;
  const int off = offsets[b];
  const int L   = offsets[b + 1] - off;
  if (m0 >= L) return;
  __shared__ ushort tile[64][66];
  const int tid = threadIdx.x;
  const int r = tid >> 4, cc = (tid & 15) * 4;
#pragma unroll
  for (int ps = 0; ps < 4; ++ps) {
    int row = r + ps * 16;
    int t = off + min(m0 + row, L - 1);
    float4 v = *(const float4*)(tv + (size_t)t * STRIDE + h * DDIM + cc);
    *(uint*)&tile[row][cc]     = pk2(v.x, v.y);
    *(uint*)&tile[row][cc + 2] = pk2(v.z, v.w);
  }
  __syncthreads();
  const int dv = tid >> 2;
  const int tc = (tid & 3) * 16;
  const int VTROW = Bb * NMAX;
  ushort* orow = vt + (size_t)(h * DDIM + dv) * VTROW + b * NMAX + m0 + tc;
  uint o[8];
#pragma unroll
  for (int j = 0; j < 8; ++j)
    o[j] = (uint)tile[tc + 2 * j][dv] | ((uint)tile[tc + 2 * j + 1][dv] << 16);
  *(uint4*)&orow[0] = make_uint4(o[0], o[1], o[2], o[3]);
  *(uint4*)&orow[8] = make_uint4(o[4], o[5], o[6], o[7]);
}

__global__ void zero_ctr(uint* ctr) { *ctr = 0u; }

template <bool PRE>
__launch_bounds__(256, 4)   // VGPR cap 128: 4 blocks/CU, no spills (R7 lesson)
__global__ void hstu_q(const float* __restrict__ tq,
                       const float* __restrict__ tk,
                       const float* __restrict__ tv,
                       const ushort* __restrict__ kbf,
                       const ushort* __restrict__ vbfT,
                       const int* __restrict__ offsets,
                       const int* __restrict__ pN,
                       const int* __restrict__ ncand,
                       const int* __restrict__ nctx,
                       float* __restrict__ out,
                       uint* __restrict__ ctr,
                       int Tm1, int Bb) {
  const int bhc    = Bb * HH;
  const int nitems = NORD * bhc;
  const int VTROW  = Bb * NMAX;

  __shared__ ushort Ks[KT * DDIM];     // K[k][d], swizzled       8 KB
  __shared__ ushort Vt[DDIM * KT];     // V^T[dv][m], swizzled    8 KB
  __shared__ ushort Ps[4 * 16 * KT];   // per-wave P strips       8 KB
  __shared__ int s_item;

  const int tid  = threadIdx.x;
  const int w    = tid >> 6;
  const int lane = tid & 63;
  const int lo   = lane & 15;
  const int hi   = lane >> 4;

  const int k_r = tid >> 3;            // K/V bf16 staging: 8 thr/row, uint4
  const int k_c = (tid & 7) * 8;       // halfword col (K) / m-chunk (V^T)

  const float invN = 1.0f / (float)pN[0];

  uint4 kpre[2], vpre[2];
  ushort* Pw = &Ps[w * 1024];

  for (;;) {
    __syncthreads();                   // prev item's LDS readers done
    if (tid == 0) s_item = (int)atomicAdd(ctr, 1u);
    __syncthreads();
    const int item = s_item;
    if (item >= nitems) return;
    const int ord = item / bhc;
    const int rem = item - ord * bhc;
    const int b = rem >> 3, h = rem & 7;
    const int qt = (ord == 0) ? 0 : (NORD - ord);
    const int off = offsets[b];
    const int L   = offsets[b + 1] - off;
    const int n0  = qt * QT;
    if (n0 >= L) continue;

    const int c = nctx[b];
    const int M = L - c + 1 - ncand[b];
    const int m_hi  = (n0 < c) ? L : min(n0 + QT, L);
    const int niter = (m_hi + KT - 1) / KT;

    // ---- issue tile-0 K/V loads (latency hides under Q load/convert) ----
    if (PRE) {
#pragma unroll
      for (int i = 0; i < 2; ++i) {
        int r = min(off + k_r + i * 32, Tm1);
        kpre[i] = *(const uint4*)(kbf + (size_t)r * STRIDE + h * DDIM + k_c);
        vpre[i] = *(const uint4*)(vbfT + (size_t)(h * DDIM + k_r + i * 32) * VTROW
                                  + b * NMAX + k_c);
      }
    }

    // ---- Q direct to registers (A-frag: row=w*16+lo, k=ks*32+hi*8+0..7) ----
    short8 qf[2];
    {
      int qr = min(off + n0 + w * 16 + lo, Tm1);
      const float* qp = tq + (size_t)qr * STRIDE + h * DDIM + hi * 8;
      float4 qa = *(const float4*)(qp);
      float4 qb = *(const float4*)(qp + 4);
      float4 qc = *(const float4*)(qp + 32);
      float4 qd = *(const float4*)(qp + 36);
      u32x4 v0 = {pk2(qa.x, qa.y), pk2(qa.z, qa.w), pk2(qb.x, qb.y), pk2(qb.z, qb.w)};
      u32x4 v1 = {pk2(qc.x, qc.y), pk2(qc.z, qc.w), pk2(qd.x, qd.y), pk2(qd.z, qd.w)};
      qf[0] = __builtin_bit_cast(short8, v0);
      qf[1] = __builtin_bit_cast(short8, v1);
    }

    // fallback K/V (fp32 sources) registers
    float4 kpf[4];
    float  vpf[16];
    if (!PRE) {
#pragma unroll
      for (int jj = 0; jj < 4; ++jj) {
        int r = min(off + (tid >> 4) + jj * 16, Tm1);
        kpf[jj] = *(const float4*)(tk + (size_t)r * STRIDE + h * DDIM + (tid & 15) * 4);
      }
#pragma unroll
      for (int j = 0; j < 16; ++j) {
        int r = min(off + w * 16 + j, Tm1);
        vpf[j] = tv[(size_t)r * STRIDE + h * DDIM + lane];
      }
    }

    // per-row mask params: valid = nok & ((m < thr) | (m == n))
    int n_r[4], thr[4];
    bool nok[4];
#pragma unroll
    for (int r = 0; r < 4; ++r) {
      const int n  = n0 + w * 16 + hi * 4 + r;
      const int an = min(max(n - c + 1, 0), M);
      n_r[r] = n;
      thr[r] = (an > 0 ? an : M) + c - 1;
      nok[r] = n < L;
    }

    f32x4 oacc[4];
#pragma unroll
    for (int i = 0; i < 4; ++i) oacc[i] = (f32x4){0.f, 0.f, 0.f, 0.f};

    for (int t = 0; t < niter; ++t) {
      const int m0 = t * KT;
      __syncthreads();  // prior iter's LDS readers done

      // ---- ds_write current K/V tile from prefetch regs ----
      if (PRE) {
#pragma unroll
        for (int i = 0; i < 2; ++i) {
          int row = k_r + i * 32;
          int sw  = k_c ^ ((row & 7) << 3);
          *(uint4*)&Ks[row * 64 + sw] = kpre[i];
          *(uint4*)&Vt[row * 64 + sw] = vpre[i];
        }
      } else {
#pragma unroll
        for (int jj = 0; jj < 4; ++jj) {
          int row = (tid >> 4) + jj * 16;
          uint2 pk;
          pk.x = pk2(kpf[jj].x, kpf[jj].y);
          pk.y = pk2(kpf[jj].z, kpf[jj].w);
          *(uint2*)&Ks[row * 64 + (((tid & 15) * 4) ^ ((row & 7) << 3))] = pk;
        }
        uint bb[8];
#pragma unroll
        for (int j = 0; j < 8; ++j) bb[j] = pk2(vpf[2 * j], vpf[2 * j + 1]);
        int s = (lane & 7) << 3;
        *(uint4*)&Vt[lane * 64 + ((w * 16)     ^ s)] = make_uint4(bb[0], bb[1], bb[2], bb[3]);
        *(uint4*)&Vt[lane * 64 + ((w * 16 + 8) ^ s)] = make_uint4(bb[4], bb[5], bb[6], bb[7]);
      }

      // ---- issue next tile's loads (consumed next iteration) ----
      if (t + 1 < niter) {
        const int mn = m0 + KT;
        if (PRE) {
#pragma unroll
          for (int i = 0; i < 2; ++i) {
            int r = min(off + mn + k_r + i * 32, Tm1);
            kpre[i] = *(const uint4*)(kbf + (size_t)r * STRIDE + h * DDIM + k_c);
            vpre[i] = *(const uint4*)(vbfT + (size_t)(h * DDIM + k_r + i * 32) * VTROW
                                      + b * NMAX + mn + k_c);
          }
        } else {
#pragma unroll
          for (int jj = 0; jj < 4; ++jj) {
            int r = min(off + mn + (tid >> 4) + jj * 16, Tm1);
            kpf[jj] = *(const float4*)(tk + (size_t)r * STRIDE + h * DDIM + (tid & 15) * 4);
          }
#pragma unroll
          for (int j = 0; j < 16; ++j) {
            int r = min(off + mn + w * 16 + j, Tm1);
            vpf[j] = tv[(size_t)r * STRIDE + h * DDIM + lane];
          }
        }
      }
      __syncthreads();  // K/V tile visible

      // ---- S = Q K^T (8 MFMA) ----
      f32x4 sacc[4];
#pragma unroll
      for (int i = 0; i < 4; ++i) sacc[i] = (f32x4){0.f, 0.f, 0.f, 0.f};
#pragma unroll
      for (int kc = 0; kc < 4; ++kc) {
        int krw = kc * 16 + lo;
#pragma unroll
        for (int ks = 0; ks < 2; ++ks) {
          short8 kf = *(const short8*)&Ks[krw * 64 + ((ks * 32 + hi * 8) ^ ((krw & 7) << 3))];
          sacc[kc] = __builtin_amdgcn_mfma_f32_16x16x32_bf16(qf[ks], kf, sacc[kc], 0, 0, 0);
        }
      }

      // ---- mask + silu/N, P -> own wave's LDS strip ----
#pragma unroll
      for (int kc = 0; kc < 4; ++kc) {
        const int mm = m0 + kc * 16 + lo;
#pragma unroll
        for (int r = 0; r < 4; ++r) {
          const bool valid = nok[r] & ((mm < thr[r]) | (mm == n_r[r]));
          float s = valid ? sacc[kc][r] : 0.f;   // silu(0)=0
          float pp = s * invN * __builtin_amdgcn_rcpf(1.f + __expf(-s));
          const int col = kc * 16 + lo;
          const int ql  = hi * 4 + r;
          Pw[ql * 64 + (col ^ ((ql & 7) << 3))] = (ushort)pk2(pp, pp);
        }
      }

      // ---- O += P V (8 MFMA); P round-trip is wave-private ----
#pragma unroll
      for (int mc = 0; mc < 2; ++mc) {
        short8 pf = *(const short8*)&Pw[lo * 64 + ((mc * 32 + hi * 8) ^ ((lo & 7) << 3))];
#pragma unroll
        for (int dvc = 0; dvc < 4; ++dvc) {
          int vrow = dvc * 16 + lo;
          short8 vf = *(const short8*)&Vt[vrow * 64 + ((mc * 32 + hi * 8) ^ ((vrow & 7) << 3))];
          oacc[dvc] = __builtin_amdgcn_mfma_f32_16x16x32_bf16(pf, vf, oacc[dvc], 0, 0, 0);
        }
      }
    }

    // ---- write out (fp32), C-frag layout ----
#pragma unroll
    for (int dvc = 0; dvc < 4; ++dvc) {
#pragma unroll
      for (int r = 0; r < 4; ++r) {
        int n = n0 + w * 16 + hi * 4 + r;
        if (n < L)
          out[(size_t)(off + n) * STRIDE + h * DDIM + dvc * 16 + lo] = oacc[dvc][r];
      }
    }
  }
}

extern "C" void kernel_launch(void* const* d_in, const int* in_sizes, int n_in,
                              void* d_out, int out_size, void* d_ws, size_t ws_size,
                              hipStream_t stream) {
  const float* tq      = (const float*)d_in[0];
  const float* tk      = (const float*)d_in[1];
  const float* tv      = (const float*)d_in[2];
  const int*   offsets = (const int*)d_in[3];
  const int*   pN      = (const int*)d_in[4];
  const int*   ncand   = (const int*)d_in[5];
  const int*   nctx    = (const int*)d_in[6];
  float*       out     = (float*)d_out;

  const int B = in_sizes[3] - 1;
  const int T = in_sizes[0] / STRIDE;

  uint*   ctr    = (uint*)d_ws;
  ushort* kbf    = (ushort*)((char*)d_ws + 16);
  size_t  kbytes = (size_t)T * STRIDE * 2;
  ushort* vbfT   = (ushort*)((char*)d_ws + 16 + kbytes);
  size_t  vbytes = (size_t)STRIDE * (size_t)B * NMAX * 2;
  const size_t need = 16 + kbytes + vbytes;

  dim3 block(256);
  const int nblocks = 1024;   // 4 blocks/CU; queue balances load

  if (ws_size >= need) {
    const int n8 = (T * STRIDE) / 8;
    int nb = (n8 + 255) / 256;
    if (nb > 2048) nb = 2048;
    conv_k<<<nb, 256, 0, stream>>>(tk, kbf, n8, ctr);
    dim3 tgrid(NMAX / 64, HH, B);
    conv_vT<<<tgrid, 256, 0, stream>>>(tv, vbfT, offsets, B);
    hstu_q<true><<<nblocks, block, 0, stream>>>(tq, tk, tv, kbf, vbfT, offsets,
                                                pN, ncand, nctx, out, ctr,
                                                T - 1, B);
  } else {
    zero_ctr<<<1, 1, 0, stream>>>(ctr);
    hstu_q<false><<<nblocks, block, 0, stream>>>(tq, tk, tv, nullptr, nullptr,
                                                 offsets, pN, ncand, nctx, out,
                                                 ctr, T - 1, B);
  }
}

// Round 9
// 76.427 us; speedup vs baseline: 1.6733x; 1.6591x over previous
//
#include <hip/hip_runtime.h>
#include <math.h>

// HSTU jagged attention, MFMA bf16, DMA-staged (global_load_lds) persistent queue.
// out = (silu(Q K^T) / N * mask) V, no softmax. H=8, D=DV=64, N=1024.
// Mask (exact collapse): valid(n,m) = (m < thr(n)) | (m == n),
//   thr(n) = (an>0 ? an : M) + c - 1, an = clamp(n-c+1,0,M), M = L-c+1-ncand.
// R9: pre-pass packs per-(b,mt,h) 16KB tile images [K 8KB | V^T 8KB] in bf16,
// ALREADY in swizzled-LDS byte layout -> hot loop stages with global_load_lds
// (zero staging VGPRs; kills the 175MB/dispatch scratch spill seen in R7/R8).

#define HH      8
#define DDIM    64
#define QT      64
#define KT      64
#define STRIDE  512
#define NMAX    1024
#define NORD    16
#define TILE_HW 8192          // ushorts per tile image (16 KB)

typedef __attribute__((ext_vector_type(8))) short short8;
typedef __attribute__((ext_vector_type(4))) float f32x4;
typedef __attribute__((ext_vector_type(4))) uint  u32x4;

// packed fp32x2 -> bf16x2 (RNE); no builtin on gfx950
static __device__ __forceinline__ uint pk2(float a, float b) {
  uint r;
  asm("v_cvt_pk_bf16_f32 %0, %1, %2" : "=v"(r) : "v"(a), "v"(b));
  return r;
}

// one 16B global->LDS DMA (dest: wave-uniform base + lane*16)
static __device__ __forceinline__ void dma16(const ushort* g, ushort* l) {
  __builtin_amdgcn_global_load_lds(
      (const __attribute__((address_space(1))) void*)g,
      (__attribute__((address_space(3))) void*)l, 16, 0, 0);
}

// ---- pre-pass: build packed swizzled tile images; zero queue counter ----
__global__ void build_tiles(const float* __restrict__ tk,
                            const float* __restrict__ tv,
                            ushort* __restrict__ tiles,
                            const int* __restrict__ offsets,
                            uint* __restrict__ ctr) {
  if (threadIdx.x == 0 && blockIdx.x == 0 && blockIdx.y == 0 && blockIdx.z == 0)
    *ctr = 0u;
  const int mt = blockIdx.x, h = blockIdx.y, b = blockIdx.z;
  const int off = offsets[b];
  const int L   = offsets[b + 1] - off;
  if (mt * 64 >= L) return;
  ushort* img = tiles + (size_t)((b * NORD + mt) * HH + h) * TILE_HW;
  const int tid = threadIdx.x;
  const int row = tid >> 2;          // 4 threads/row
  const int c0  = (tid & 3) * 16;    // 16 cols each
  const int m   = mt * 64 + row;
  const int sw  = (row & 7) << 3;

  __shared__ ushort tr[64][66];      // V transpose staging (padded)

  // K rows -> img[0..4095] (swizzled LDS image)
  {
    uint u[8];
    if (m < L) {
      const float* s = tk + (size_t)(off + m) * STRIDE + h * DDIM + c0;
      float4 a = *(const float4*)(s),     b4 = *(const float4*)(s + 4);
      float4 c4 = *(const float4*)(s + 8), d4 = *(const float4*)(s + 12);
      u[0] = pk2(a.x, a.y);  u[1] = pk2(a.z, a.w);
      u[2] = pk2(b4.x, b4.y); u[3] = pk2(b4.z, b4.w);
      u[4] = pk2(c4.x, c4.y); u[5] = pk2(c4.z, c4.w);
      u[6] = pk2(d4.x, d4.y); u[7] = pk2(d4.z, d4.w);
    } else {
#pragma unroll
      for (int j = 0; j < 8; ++j) u[j] = 0u;
    }
    *(uint4*)&img[row * 64 + (c0 ^ sw)]       = make_uint4(u[0], u[1], u[2], u[3]);
    *(uint4*)&img[row * 64 + ((c0 + 8) ^ sw)] = make_uint4(u[4], u[5], u[6], u[7]);
  }
  // V rows -> LDS (bf16), for transpose
  {
    uint u[8];
    if (m < L) {
      const float* s = tv + (size_t)(off + m) * STRIDE + h * DDIM + c0;
      float4 a = *(const float4*)(s),     b4 = *(const float4*)(s + 4);
      float4 c4 = *(const float4*)(s + 8), d4 = *(const float4*)(s + 12);
      u[0] = pk2(a.x, a.y);  u[1] = pk2(a.z, a.w);
      u[2] = pk2(b4.x, b4.y); u[3] = pk2(b4.z, b4.w);
      u[4] = pk2(c4.x, c4.y); u[5] = pk2(c4.z, c4.w);
      u[6] = pk2(d4.x, d4.y); u[7] = pk2(d4.z, d4.w);
    } else {
#pragma unroll
      for (int j = 0; j < 8; ++j) u[j] = 0u;
    }
#pragma unroll
    for (int j = 0; j < 8; ++j) *(uint*)&tr[row][c0 + 2 * j] = u[j];
  }
  __syncthreads();
  // V^T -> img[4096..8191]: dv=row, m-chunk=c0 (swizzled)
  {
    uint u[8];
#pragma unroll
    for (int j = 0; j < 8; ++j)
      u[j] = (uint)tr[c0 + 2 * j][row] | ((uint)tr[c0 + 2 * j + 1][row] << 16);
    *(uint4*)&img[4096 + row * 64 + (c0 ^ sw)]       = make_uint4(u[0], u[1], u[2], u[3]);
    *(uint4*)&img[4096 + row * 64 + ((c0 + 8) ^ sw)] = make_uint4(u[4], u[5], u[6], u[7]);
  }
}

__global__ void zero_ctr(uint* ctr) { *ctr = 0u; }

// ---- main: DMA-staged persistent-queue kernel ----
__launch_bounds__(256, 4)
__global__ void hstu_dma(const float* __restrict__ tq,
                         const ushort* __restrict__ tiles,
                         const int* __restrict__ offsets,
                         const int* __restrict__ pN,
                         const int* __restrict__ ncand,
                         const int* __restrict__ nctx,
                         float* __restrict__ out,
                         uint* __restrict__ ctr,
                         int Tm1, int Bb) {
  const int bhc    = Bb * HH;
  const int nitems = NORD * bhc;

  __shared__ ushort KV[2][TILE_HW];  // double-buffered [K 8KB | V^T 8KB]  32 KB
  __shared__ ushort Ps[4 * 1024];    // per-wave P strips; Ps[0:1] = item bcast

  const int tid  = threadIdx.x;
  const int w    = tid >> 6;
  const int lane = tid & 63;
  const int lo   = lane & 15;
  const int hi   = lane >> 4;

  const float invN = 1.0f / (float)pN[0];
  ushort* Pw = &Ps[w * 1024];

  for (;;) {
    __syncthreads();                         // prev item fully consumed
    if (tid == 0) *(int*)&Ps[0] = (int)atomicAdd(ctr, 1u);
    __syncthreads();
    const int item = *(const int*)&Ps[0];    // read before loop-top barrier,
    if (item >= nitems) return;              // i.e. before any P write
    const int ord = item / bhc;
    const int rem = item - ord * bhc;
    const int b = rem >> 3, h = rem & 7;
    const int qt = (ord == 0) ? 0 : (NORD - ord);
    const int off = offsets[b];
    const int L   = offsets[b + 1] - off;
    const int n0  = qt * QT;
    if (n0 >= L) continue;

    const int c = nctx[b];
    const int M = L - c + 1 - ncand[b];
    const int m_hi  = (n0 < c) ? L : min(n0 + QT, L);
    const int niter = (m_hi + KT - 1) / KT;

    const ushort* ibase = tiles + (size_t)(b * NORD * HH + h) * TILE_HW;

    // prologue: DMA tile 0 into KV[0] (4 x 16B per lane per wave = 16 KB/block)
    {
      const ushort* src = ibase + w * 2048 + lane * 8;
      ushort* dst = &KV[0][w * 2048];
#pragma unroll
      for (int i = 0; i < 4; ++i) dma16(src + i * 512, dst + i * 512);
    }

    // Q -> registers (A-frag: row = w*16+lo, k = ks*32 + hi*8 + 0..7)
    short8 qf[2];
    {
      int qr = min(off + n0 + w * 16 + lo, Tm1);
      const float* qp = tq + (size_t)qr * STRIDE + h * DDIM + hi * 8;
      float4 qa = *(const float4*)(qp);
      float4 qb = *(const float4*)(qp + 4);
      float4 qc = *(const float4*)(qp + 32);
      float4 qd = *(const float4*)(qp + 36);
      u32x4 v0 = {pk2(qa.x, qa.y), pk2(qa.z, qa.w), pk2(qb.x, qb.y), pk2(qb.z, qb.w)};
      u32x4 v1 = {pk2(qc.x, qc.y), pk2(qc.z, qc.w), pk2(qd.x, qd.y), pk2(qd.z, qd.w)};
      qf[0] = __builtin_bit_cast(short8, v0);
      qf[1] = __builtin_bit_cast(short8, v1);
    }

    // per-row mask params: valid = nok & ((m < thr) | (m == n))
    int n_r[4], thr[4];
    bool nok[4];
#pragma unroll
    for (int r = 0; r < 4; ++r) {
      const int n  = n0 + w * 16 + hi * 4 + r;
      const int an = min(max(n - c + 1, 0), M);
      n_r[r] = n;
      thr[r] = (an > 0 ? an : M) + c - 1;
      nok[r] = n < L;
    }

    f32x4 oacc[4];
#pragma unroll
    for (int i = 0; i < 4; ++i) oacc[i] = (f32x4){0.f, 0.f, 0.f, 0.f};

    for (int t = 0; t < niter; ++t) {
      __syncthreads();   // drains tile-t DMA (auto vmcnt0); gates buf (t+1)&1 reuse

      // issue next tile's DMA; lands during compute, drained at next barrier
      if (t + 1 < niter) {
        const ushort* src = ibase + (size_t)(t + 1) * (HH * TILE_HW)
                            + w * 2048 + lane * 8;
        ushort* dst = &KV[(t + 1) & 1][w * 2048];
#pragma unroll
        for (int i = 0; i < 4; ++i) dma16(src + i * 512, dst + i * 512);
      }

      const ushort* Kb = KV[t & 1];
      const ushort* Vb = Kb + 4096;
      const int m0 = t * KT;

      // S = Q K^T, fused per-kc mask+silu+P-write (sacc live range = 4 regs)
#pragma unroll
      for (int kc = 0; kc < 4; ++kc) {
        const int krw = kc * 16 + lo;
        const int ksw = (krw & 7) << 3;
        short8 kf0 = *(const short8*)&Kb[krw * 64 + ((hi * 8) ^ ksw)];
        short8 kf1 = *(const short8*)&Kb[krw * 64 + ((32 + hi * 8) ^ ksw)];
        f32x4 s4 = (f32x4){0.f, 0.f, 0.f, 0.f};
        s4 = __builtin_amdgcn_mfma_f32_16x16x32_bf16(qf[0], kf0, s4, 0, 0, 0);
        s4 = __builtin_amdgcn_mfma_f32_16x16x32_bf16(qf[1], kf1, s4, 0, 0, 0);
        const int mm = m0 + kc * 16 + lo;
#pragma unroll
        for (int r = 0; r < 4; ++r) {
          const bool valid = nok[r] & ((mm < thr[r]) | (mm == n_r[r]));
          float s = valid ? s4[r] : 0.f;     // silu(0)=0; no NaN path
          float pp = s * invN * __builtin_amdgcn_rcpf(1.f + __expf(-s));
          const int ql = hi * 4 + r;
          Pw[ql * 64 + ((kc * 16 + lo) ^ ((ql & 7) << 3))] = (ushort)pk2(pp, pp);
        }
      }

      // O += P V (wave-private P round-trip, no barrier)
#pragma unroll
      for (int mc = 0; mc < 2; ++mc) {
        short8 pf = *(const short8*)&Pw[lo * 64 + ((mc * 32 + hi * 8) ^ ((lo & 7) << 3))];
#pragma unroll
        for (int dvc = 0; dvc < 4; ++dvc) {
          const int vrow = dvc * 16 + lo;
          short8 vf = *(const short8*)&Vb[vrow * 64 + ((mc * 32 + hi * 8) ^ ((vrow & 7) << 3))];
          oacc[dvc] = __builtin_amdgcn_mfma_f32_16x16x32_bf16(pf, vf, oacc[dvc], 0, 0, 0);
        }
      }
    }

    // write out (fp32), C-frag layout: row = 4*hi+r, col = lo (per 16-block)
#pragma unroll
    for (int dvc = 0; dvc < 4; ++dvc) {
#pragma unroll
      for (int r = 0; r < 4; ++r) {
        int n = n0 + w * 16 + hi * 4 + r;
        if (n < L)
          out[(size_t)(off + n) * STRIDE + h * DDIM + dvc * 16 + lo] = oacc[dvc][r];
      }
    }
  }
}

// ---- fallback (ws too small): R8 reg-staged fp32 path, known-good ----
__launch_bounds__(256)
__global__ void hstu_fb(const float* __restrict__ tq,
                        const float* __restrict__ tk,
                        const float* __restrict__ tv,
                        const int* __restrict__ offsets,
                        const int* __restrict__ pN,
                        const int* __restrict__ ncand,
                        const int* __restrict__ nctx,
                        float* __restrict__ out,
                        uint* __restrict__ ctr,
                        int Tm1, int Bb) {
  const int bhc    = Bb * HH;
  const int nitems = NORD * bhc;

  __shared__ ushort Ks[KT * DDIM];
  __shared__ ushort Vt[DDIM * KT];
  __shared__ ushort Ps[4 * 1024];
  __shared__ int s_item;

  const int tid  = threadIdx.x;
  const int w    = tid >> 6;
  const int lane = tid & 63;
  const int lo   = lane & 15;
  const int hi   = lane >> 4;
  const float invN = 1.0f / (float)pN[0];
  ushort* Pw = &Ps[w * 1024];

  for (;;) {
    __syncthreads();
    if (tid == 0) s_item = (int)atomicAdd(ctr, 1u);
    __syncthreads();
    const int item = s_item;
    if (item >= nitems) return;
    const int ord = item / bhc;
    const int rem = item - ord * bhc;
    const int b = rem >> 3, h = rem & 7;
    const int qt = (ord == 0) ? 0 : (NORD - ord);
    const int off = offsets[b];
    const int L   = offsets[b + 1] - off;
    const int n0  = qt * QT;
    if (n0 >= L) continue;

    const int c = nctx[b];
    const int M = L - c + 1 - ncand[b];
    const int m_hi  = (n0 < c) ? L : min(n0 + QT, L);
    const int niter = (m_hi + KT - 1) / KT;

    short8 qf[2];
    {
      int qr = min(off + n0 + w * 16 + lo, Tm1);
      const float* qp = tq + (size_t)qr * STRIDE + h * DDIM + hi * 8;
      float4 qa = *(const float4*)(qp);
      float4 qb = *(const float4*)(qp + 4);
      float4 qc = *(const float4*)(qp + 32);
      float4 qd = *(const float4*)(qp + 36);
      u32x4 v0 = {pk2(qa.x, qa.y), pk2(qa.z, qa.w), pk2(qb.x, qb.y), pk2(qb.z, qb.w)};
      u32x4 v1 = {pk2(qc.x, qc.y), pk2(qc.z, qc.w), pk2(qd.x, qd.y), pk2(qd.z, qd.w)};
      qf[0] = __builtin_bit_cast(short8, v0);
      qf[1] = __builtin_bit_cast(short8, v1);
    }

    int n_r[4], thr[4];
    bool nok[4];
#pragma unroll
    for (int r = 0; r < 4; ++r) {
      const int n  = n0 + w * 16 + hi * 4 + r;
      const int an = min(max(n - c + 1, 0), M);
      n_r[r] = n;
      thr[r] = (an > 0 ? an : M) + c - 1;
      nok[r] = n < L;
    }

    f32x4 oacc[4];
#pragma unroll
    for (int i = 0; i < 4; ++i) oacc[i] = (f32x4){0.f, 0.f, 0.f, 0.f};

    for (int t = 0; t < niter; ++t) {
      const int m0 = t * KT;
      __syncthreads();
      // stage K/V from fp32 sources
#pragma unroll
      for (int jj = 0; jj < 4; ++jj) {
        int row = (tid >> 4) + jj * 16;
        int r2  = min(off + m0 + row, Tm1);
        float4 kv = *(const float4*)(tk + (size_t)r2 * STRIDE + h * DDIM + (tid & 15) * 4);
        uint2 pk;
        pk.x = pk2(kv.x, kv.y);
        pk.y = pk2(kv.z, kv.w);
        *(uint2*)&Ks[row * 64 + (((tid & 15) * 4) ^ ((row & 7) << 3))] = pk;
      }
      {
        uint bb[8];
#pragma unroll
        for (int j = 0; j < 8; ++j) {
          int ra = min(off + m0 + w * 16 + 2 * j,     Tm1);
          int rb = min(off + m0 + w * 16 + 2 * j + 1, Tm1);
          float va = tv[(size_t)ra * STRIDE + h * DDIM + lane];
          float vb = tv[(size_t)rb * STRIDE + h * DDIM + lane];
          bb[j] = pk2(va, vb);
        }
        int s = (lane & 7) << 3;
        *(uint4*)&Vt[lane * 64 + ((w * 16)     ^ s)] = make_uint4(bb[0], bb[1], bb[2], bb[3]);
        *(uint4*)&Vt[lane * 64 + ((w * 16 + 8) ^ s)] = make_uint4(bb[4], bb[5], bb[6], bb[7]);
      }
      __syncthreads();

#pragma unroll
      for (int kc = 0; kc < 4; ++kc) {
        const int krw = kc * 16 + lo;
        const int ksw = (krw & 7) << 3;
        short8 kf0 = *(const short8*)&Ks[krw * 64 + ((hi * 8) ^ ksw)];
        short8 kf1 = *(const short8*)&Ks[krw * 64 + ((32 + hi * 8) ^ ksw)];
        f32x4 s4 = (f32x4){0.f, 0.f, 0.f, 0.f};
        s4 = __builtin_amdgcn_mfma_f32_16x16x32_bf16(qf[0], kf0, s4, 0, 0, 0);
        s4 = __builtin_amdgcn_mfma_f32_16x16x32_bf16(qf[1], kf1, s4, 0, 0, 0);
        const int mm = m0 + kc * 16 + lo;
#pragma unroll
        for (int r = 0; r < 4; ++r) {
          const bool valid = nok[r] & ((mm < thr[r]) | (mm == n_r[r]));
          float s = valid ? s4[r] : 0.f;
          float pp = s * invN * __builtin_amdgcn_rcpf(1.f + __expf(-s));
          const int ql = hi * 4 + r;
          Pw[ql * 64 + ((kc * 16 + lo) ^ ((ql & 7) << 3))] = (ushort)pk2(pp, pp);
        }
      }

#pragma unroll
      for (int mc = 0; mc < 2; ++mc) {
        short8 pf = *(const short8*)&Pw[lo * 64 + ((mc * 32 + hi * 8) ^ ((lo & 7) << 3))];
#pragma unroll
        for (int dvc = 0; dvc < 4; ++dvc) {
          const int vrow = dvc * 16 + lo;
          short8 vf = *(const short8*)&Vt[vrow * 64 + ((mc * 32 + hi * 8) ^ ((vrow & 7) << 3))];
          oacc[dvc] = __builtin_amdgcn_mfma_f32_16x16x32_bf16(pf, vf, oacc[dvc], 0, 0, 0);
        }
      }
    }

#pragma unroll
    for (int dvc = 0; dvc < 4; ++dvc) {
#pragma unroll
      for (int r = 0; r < 4; ++r) {
        int n = n0 + w * 16 + hi * 4 + r;
        if (n < L)
          out[(size_t)(off + n) * STRIDE + h * DDIM + dvc * 16 + lo] = oacc[dvc][r];
      }
    }
  }
}

extern "C" void kernel_launch(void* const* d_in, const int* in_sizes, int n_in,
                              void* d_out, int out_size, void* d_ws, size_t ws_size,
                              hipStream_t stream) {
  const float* tq      = (const float*)d_in[0];
  const float* tk      = (const float*)d_in[1];
  const float* tv      = (const float*)d_in[2];
  const int*   offsets = (const int*)d_in[3];
  const int*   pN      = (const int*)d_in[4];
  const int*   ncand   = (const int*)d_in[5];
  const int*   nctx    = (const int*)d_in[6];
  float*       out     = (float*)d_out;

  const int B = in_sizes[3] - 1;
  const int T = in_sizes[0] / STRIDE;

  uint*   ctr   = (uint*)d_ws;
  ushort* tiles = (ushort*)((char*)d_ws + 256);
  const size_t need = 256 + (size_t)B * NORD * HH * TILE_HW * sizeof(ushort);

  dim3 block(256);
  const int nblocks = 1024;   // 4 blocks/CU; LPT queue balances load

  if (ws_size >= need) {
    dim3 tgrid(NORD, HH, B);
    build_tiles<<<tgrid, block, 0, stream>>>(tk, tv, tiles, offsets, ctr);
    hstu_dma<<<nblocks, block, 0, stream>>>(tq, tiles, offsets, pN, ncand,
                                            nctx, out, ctr, T - 1, B);
  } else {
    zero_ctr<<<1, 1, 0, stream>>>(ctr);
    hstu_fb<<<nblocks, block, 0, stream>>>(tq, tk, tv, offsets, pN, ncand,
                                           nctx, out, ctr, T - 1, B);
  }
}

// Round 10
// 72.485 us; speedup vs baseline: 1.7643x; 1.0544x over previous
//
#include <hip/hip_runtime.h>
#include <math.h>

// HSTU jagged attention, MFMA bf16, DMA-staged, static XCD-affine LPT schedule.
// out = (silu(Q K^T) / N * mask) V, no softmax. H=8, D=DV=64, N=1024.
// Mask (exact collapse): valid(n,m) = (m < thr(n)) | (m == n),
//   thr(n) = (an>0 ? an : M) + c - 1, an = clamp(n-c+1,0,M), M = L-c+1-ncand.
// R10: scheduler pre-pass pairs batches (heavy+light nq) into 8 groups, one per
// XCD (~3.25MB tiles each -> fits 4MB XCD L2); group g items run only on blocks
// ==g (mod 8); snake-deal in desc-cost order (LPT). No atomics/broadcast.

#define HH      8
#define DDIM    64
#define QT      64
#define KT      64
#define STRIDE  512
#define NMAX    1024
#define NORD    16
#define TILE_HW 8192          // ushorts per tile image (16 KB)
#define NBLK    1024
#define SLOTS   8

typedef __attribute__((ext_vector_type(8))) short short8;
typedef __attribute__((ext_vector_type(4))) float f32x4;
typedef __attribute__((ext_vector_type(4))) uint  u32x4;

static __device__ __forceinline__ uint pk2(float a, float b) {
  uint r;
  asm("v_cvt_pk_bf16_f32 %0, %1, %2" : "=v"(r) : "v"(a), "v"(b));
  return r;
}

static __device__ __forceinline__ void dma16(const ushort* g, ushort* l) {
  __builtin_amdgcn_global_load_lds(
      (const __attribute__((address_space(1))) void*)g,
      (__attribute__((address_space(3))) void*)l, 16, 0, 0);
}

// ---- pre-pass A: packed swizzled tile images [K 8KB | V^T 8KB]; zero ctr ----
__global__ void build_tiles(const float* __restrict__ tk,
                            const float* __restrict__ tv,
                            ushort* __restrict__ tiles,
                            const int* __restrict__ offsets,
                            uint* __restrict__ ctr) {
  if (threadIdx.x == 0 && blockIdx.x == 0 && blockIdx.y == 0 && blockIdx.z == 0)
    *ctr = 0u;
  const int mt = blockIdx.x, h = blockIdx.y, b = blockIdx.z;
  const int off = offsets[b];
  const int L   = offsets[b + 1] - off;
  if (mt * 64 >= L) return;
  ushort* img = tiles + (size_t)((b * NORD + mt) * HH + h) * TILE_HW;
  const int tid = threadIdx.x;
  const int row = tid >> 2;
  const int c0  = (tid & 3) * 16;
  const int m   = mt * 64 + row;
  const int sw  = (row & 7) << 3;

  __shared__ ushort tr[64][66];

  {
    uint u[8];
    if (m < L) {
      const float* s = tk + (size_t)(off + m) * STRIDE + h * DDIM + c0;
      float4 a = *(const float4*)(s),      b4 = *(const float4*)(s + 4);
      float4 c4 = *(const float4*)(s + 8), d4 = *(const float4*)(s + 12);
      u[0] = pk2(a.x, a.y);   u[1] = pk2(a.z, a.w);
      u[2] = pk2(b4.x, b4.y); u[3] = pk2(b4.z, b4.w);
      u[4] = pk2(c4.x, c4.y); u[5] = pk2(c4.z, c4.w);
      u[6] = pk2(d4.x, d4.y); u[7] = pk2(d4.z, d4.w);
    } else {
#pragma unroll
      for (int j = 0; j < 8; ++j) u[j] = 0u;
    }
    *(uint4*)&img[row * 64 + (c0 ^ sw)]       = make_uint4(u[0], u[1], u[2], u[3]);
    *(uint4*)&img[row * 64 + ((c0 + 8) ^ sw)] = make_uint4(u[4], u[5], u[6], u[7]);
  }
  {
    uint u[8];
    if (m < L) {
      const float* s = tv + (size_t)(off + m) * STRIDE + h * DDIM + c0;
      float4 a = *(const float4*)(s),      b4 = *(const float4*)(s + 4);
      float4 c4 = *(const float4*)(s + 8), d4 = *(const float4*)(s + 12);
      u[0] = pk2(a.x, a.y);   u[1] = pk2(a.z, a.w);
      u[2] = pk2(b4.x, b4.y); u[3] = pk2(b4.z, b4.w);
      u[4] = pk2(c4.x, c4.y); u[5] = pk2(c4.z, c4.w);
      u[6] = pk2(d4.x, d4.y); u[7] = pk2(d4.z, d4.w);
    } else {
#pragma unroll
      for (int j = 0; j < 8; ++j) u[j] = 0u;
    }
#pragma unroll
    for (int j = 0; j < 8; ++j) *(uint*)&tr[row][c0 + 2 * j] = u[j];
  }
  __syncthreads();
  {
    uint u[8];
#pragma unroll
    for (int j = 0; j < 8; ++j)
      u[j] = (uint)tr[c0 + 2 * j][row] | ((uint)tr[c0 + 2 * j + 1][row] << 16);
    *(uint4*)&img[4096 + row * 64 + (c0 ^ sw)]       = make_uint4(u[0], u[1], u[2], u[3]);
    *(uint4*)&img[4096 + row * 64 + ((c0 + 8) ^ sw)] = make_uint4(u[4], u[5], u[6], u[7]);
  }
}

// ---- pre-pass B: static XCD-affine LPT schedule (1 block) ----
// item (b,h,qt) cost = (qt==0 ? nq : qt+1). Batches sorted by nq desc; rank r
// pairs with rank B-1-r -> group r%8. Within group: desc-cost rank -> snake
// over the group's 128 blocks {g, g+8, ..., g+8*127}.
__global__ void make_sched(const int* __restrict__ offsets, int Bb,
                           short* __restrict__ sched) {
  __shared__ int nq_s[16];
  __shared__ int grp_s[16];
  __shared__ int hist[8][18];
  __shared__ int base_s[8][18];
  __shared__ int cur_s[8][18];
  __shared__ int slotcnt[NBLK];
  const int tid = threadIdx.x;
  if (tid < Bb) {
    int L = offsets[tid + 1] - offsets[tid];
    nq_s[tid] = (L + QT - 1) / QT;
  }
  for (int i = tid; i < NBLK; i += 256) slotcnt[i] = 0;
  if (tid < 144) { ((int*)hist)[tid] = 0; ((int*)cur_s)[tid] = 0; }
  __syncthreads();
  if (tid == 0) {
    int idx[16];
    for (int i = 0; i < Bb; ++i) idx[i] = i;
    for (int i = 1; i < Bb; ++i) {           // insertion sort, nq desc
      int k = idx[i], j = i - 1;
      while (j >= 0 && nq_s[idx[j]] < nq_s[k]) { idx[j + 1] = idx[j]; --j; }
      idx[j + 1] = k;
    }
    for (int r = 0; r < Bb; ++r)
      grp_s[idx[r]] = (r < Bb / 2) ? (r % 8) : ((Bb - 1 - r) % 8);
  }
  __syncthreads();
  const int nitems = Bb * HH * NORD;
  for (int it = tid; it < nitems; it += 256) {
    int b = it >> 7, h = (it >> 4) & 7, qt = it & 15;
    int nq = nq_s[b];
    if (qt >= nq) continue;
    int cost = (qt == 0) ? nq : qt + 1;
    atomicAdd(&hist[grp_s[b]][cost], 1);
  }
  __syncthreads();
  if (tid < 8) {
    int acc = 0;
    for (int c = 16; c >= 1; --c) { base_s[tid][c] = acc; acc += hist[tid][c]; }
  }
  __syncthreads();
  for (int it = tid; it < nitems; it += 256) {
    int b = it >> 7, h = (it >> 4) & 7, qt = it & 15;
    int nq = nq_s[b];
    if (qt >= nq) continue;
    int cost = (qt == 0) ? nq : qt + 1;
    int g    = grp_s[b];
    int rank = base_s[g][cost] + atomicAdd(&cur_s[g][cost], 1);
    int pos  = rank & 255;
    int lb   = (pos < 128) ? pos : 255 - pos;   // snake
    int blk  = g + 8 * lb;                       // stays on XCD g
    int slot = atomicAdd(&slotcnt[blk], 1);
    if (slot < SLOTS) sched[blk * SLOTS + slot] = (short)((b << 7) | (h << 4) | qt);
  }
  __syncthreads();
  for (int i = tid; i < NBLK * SLOTS; i += 256) {
    int blk = i / SLOTS, slot = i - blk * SLOTS;
    if (slot >= min(slotcnt[blk], SLOTS)) sched[i] = (short)-1;
  }
}

__global__ void zero_ctr(uint* ctr) { *ctr = 0u; }

// ---- main: DMA-staged, statically scheduled ----
__launch_bounds__(256, 4)
__global__ void hstu_s(const float* __restrict__ tq,
                       const ushort* __restrict__ tiles,
                       const short* __restrict__ sched,
                       const int* __restrict__ offsets,
                       const int* __restrict__ pN,
                       const int* __restrict__ ncand,
                       const int* __restrict__ nctx,
                       float* __restrict__ out, int Tm1) {
  __shared__ ushort KV[2][TILE_HW];  // double-buffered [K 8KB | V^T 8KB]  32 KB
  __shared__ ushort Ps[4 * 1024];    // per-wave P strips                  8 KB

  const int tid  = threadIdx.x;
  const int w    = tid >> 6;
  const int lane = tid & 63;
  const int lo   = lane & 15;
  const int hi   = lane >> 4;

  const float invN = 1.0f / (float)pN[0];
  ushort* Pw = &Ps[w * 1024];
  const short* my = sched + blockIdx.x * SLOTS;

  for (int slot = 0; slot < SLOTS; ++slot) {
    const int e = my[slot];
    if (e < 0) return;
    const int b = (e >> 7) & 15, h = (e >> 4) & 7, qt = e & 15;
    const int off = offsets[b];
    const int L   = offsets[b + 1] - off;
    const int n0  = qt * QT;
    if (n0 >= L) continue;                   // scheduler guarantees; belt+braces

    const int c = nctx[b];
    const int M = L - c + 1 - ncand[b];
    const int m_hi  = (n0 < c) ? L : min(n0 + QT, L);
    const int niter = (m_hi + KT - 1) / KT;

    const ushort* ibase = tiles + (size_t)(b * NORD * HH + h) * TILE_HW;

    __syncthreads();                         // prev item's LDS fully consumed

    // prologue: DMA tile 0 into KV[0]
    {
      const ushort* src = ibase + w * 2048 + lane * 8;
      ushort* dst = &KV[0][w * 2048];
#pragma unroll
      for (int i = 0; i < 4; ++i) dma16(src + i * 512, dst + i * 512);
    }

    // Q -> registers (A-frag: row = w*16+lo, k = ks*32 + hi*8 + 0..7)
    short8 qf[2];
    {
      int qr = min(off + n0 + w * 16 + lo, Tm1);
      const float* qp = tq + (size_t)qr * STRIDE + h * DDIM + hi * 8;
      float4 qa = *(const float4*)(qp);
      float4 qb = *(const float4*)(qp + 4);
      float4 qc = *(const float4*)(qp + 32);
      float4 qd = *(const float4*)(qp + 36);
      u32x4 v0 = {pk2(qa.x, qa.y), pk2(qa.z, qa.w), pk2(qb.x, qb.y), pk2(qb.z, qb.w)};
      u32x4 v1 = {pk2(qc.x, qc.y), pk2(qc.z, qc.w), pk2(qd.x, qd.y), pk2(qd.z, qd.w)};
      qf[0] = __builtin_bit_cast(short8, v0);
      qf[1] = __builtin_bit_cast(short8, v1);
    }

    int n_r[4], thr[4];
    bool nok[4];
#pragma unroll
    for (int r = 0; r < 4; ++r) {
      const int n  = n0 + w * 16 + hi * 4 + r;
      const int an = min(max(n - c + 1, 0), M);
      n_r[r] = n;
      thr[r] = (an > 0 ? an : M) + c - 1;
      nok[r] = n < L;
    }

    f32x4 oacc[4];
#pragma unroll
    for (int i = 0; i < 4; ++i) oacc[i] = (f32x4){0.f, 0.f, 0.f, 0.f};

    for (int t = 0; t < niter; ++t) {
      __syncthreads();   // drains tile-t DMA; gates buf (t+1)&1 reuse

      if (t + 1 < niter) {
        const ushort* src = ibase + (size_t)(t + 1) * (HH * TILE_HW)
                            + w * 2048 + lane * 8;
        ushort* dst = &KV[(t + 1) & 1][w * 2048];
#pragma unroll
        for (int i = 0; i < 4; ++i) dma16(src + i * 512, dst + i * 512);
      }

      const ushort* Kb = KV[t & 1];
      const ushort* Vb = Kb + 4096;
      const int m0 = t * KT;

      // S = Q K^T, fused per-kc mask+silu+P-write
#pragma unroll
      for (int kc = 0; kc < 4; ++kc) {
        const int krw = kc * 16 + lo;
        const int ksw = (krw & 7) << 3;
        short8 kf0 = *(const short8*)&Kb[krw * 64 + ((hi * 8) ^ ksw)];
        short8 kf1 = *(const short8*)&Kb[krw * 64 + ((32 + hi * 8) ^ ksw)];
        f32x4 s4 = (f32x4){0.f, 0.f, 0.f, 0.f};
        s4 = __builtin_amdgcn_mfma_f32_16x16x32_bf16(qf[0], kf0, s4, 0, 0, 0);
        s4 = __builtin_amdgcn_mfma_f32_16x16x32_bf16(qf[1], kf1, s4, 0, 0, 0);
        const int mm = m0 + kc * 16 + lo;
#pragma unroll
        for (int r = 0; r < 4; ++r) {
          const bool valid = nok[r] & ((mm < thr[r]) | (mm == n_r[r]));
          float s = valid ? s4[r] : 0.f;     // silu(0)=0; no NaN path
          float pp = s * invN * __builtin_amdgcn_rcpf(1.f + __expf(-s));
          const int ql = hi * 4 + r;
          Pw[ql * 64 + ((kc * 16 + lo) ^ ((ql & 7) << 3))] = (ushort)pk2(pp, pp);
        }
      }

      // O += P V (wave-private P round-trip, no barrier)
#pragma unroll
      for (int mc = 0; mc < 2; ++mc) {
        short8 pf = *(const short8*)&Pw[lo * 64 + ((mc * 32 + hi * 8) ^ ((lo & 7) << 3))];
#pragma unroll
        for (int dvc = 0; dvc < 4; ++dvc) {
          const int vrow = dvc * 16 + lo;
          short8 vf = *(const short8*)&Vb[vrow * 64 + ((mc * 32 + hi * 8) ^ ((vrow & 7) << 3))];
          oacc[dvc] = __builtin_amdgcn_mfma_f32_16x16x32_bf16(pf, vf, oacc[dvc], 0, 0, 0);
        }
      }
    }

    // write out (fp32), C-frag layout
#pragma unroll
    for (int dvc = 0; dvc < 4; ++dvc) {
#pragma unroll
      for (int r = 0; r < 4; ++r) {
        int n = n0 + w * 16 + hi * 4 + r;
        if (n < L)
          out[(size_t)(off + n) * STRIDE + h * DDIM + dvc * 16 + lo] = oacc[dvc][r];
      }
    }
  }
}

// ---- fallback (ws too small / B>16): R9 reg-staged fp32 queue path ----
__launch_bounds__(256)
__global__ void hstu_fb(const float* __restrict__ tq,
                        const float* __restrict__ tk,
                        const float* __restrict__ tv,
                        const int* __restrict__ offsets,
                        const int* __restrict__ pN,
                        const int* __restrict__ ncand,
                        const int* __restrict__ nctx,
                        float* __restrict__ out,
                        uint* __restrict__ ctr,
                        int Tm1, int Bb) {
  const int bhc    = Bb * HH;
  const int nitems = NORD * bhc;

  __shared__ ushort Ks[KT * DDIM];
  __shared__ ushort Vt[DDIM * KT];
  __shared__ ushort Ps[4 * 1024];
  __shared__ int s_item;

  const int tid  = threadIdx.x;
  const int w    = tid >> 6;
  const int lane = tid & 63;
  const int lo   = lane & 15;
  const int hi   = lane >> 4;
  const float invN = 1.0f / (float)pN[0];
  ushort* Pw = &Ps[w * 1024];

  for (;;) {
    __syncthreads();
    if (tid == 0) s_item = (int)atomicAdd(ctr, 1u);
    __syncthreads();
    const int item = s_item;
    if (item >= nitems) return;
    const int ord = item / bhc;
    const int rem = item - ord * bhc;
    const int b = rem / HH, h = rem - b * HH;
    const int qt = (ord == 0) ? 0 : (NORD - ord);
    const int off = offsets[b];
    const int L   = offsets[b + 1] - off;
    const int n0  = qt * QT;
    if (n0 >= L) continue;

    const int c = nctx[b];
    const int M = L - c + 1 - ncand[b];
    const int m_hi  = (n0 < c) ? L : min(n0 + QT, L);
    const int niter = (m_hi + KT - 1) / KT;

    short8 qf[2];
    {
      int qr = min(off + n0 + w * 16 + lo, Tm1);
      const float* qp = tq + (size_t)qr * STRIDE + h * DDIM + hi * 8;
      float4 qa = *(const float4*)(qp);
      float4 qb = *(const float4*)(qp + 4);
      float4 qc = *(const float4*)(qp + 32);
      float4 qd = *(const float4*)(qp + 36);
      u32x4 v0 = {pk2(qa.x, qa.y), pk2(qa.z, qa.w), pk2(qb.x, qb.y), pk2(qb.z, qb.w)};
      u32x4 v1 = {pk2(qc.x, qc.y), pk2(qc.z, qc.w), pk2(qd.x, qd.y), pk2(qd.z, qd.w)};
      qf[0] = __builtin_bit_cast(short8, v0);
      qf[1] = __builtin_bit_cast(short8, v1);
    }

    int n_r[4], thr[4];
    bool nok[4];
#pragma unroll
    for (int r = 0; r < 4; ++r) {
      const int n  = n0 + w * 16 + hi * 4 + r;
      const int an = min(max(n - c + 1, 0), M);
      n_r[r] = n;
      thr[r] = (an > 0 ? an : M) + c - 1;
      nok[r] = n < L;
    }

    f32x4 oacc[4];
#pragma unroll
    for (int i = 0; i < 4; ++i) oacc[i] = (f32x4){0.f, 0.f, 0.f, 0.f};

    for (int t = 0; t < niter; ++t) {
      const int m0 = t * KT;
      __syncthreads();
#pragma unroll
      for (int jj = 0; jj < 4; ++jj) {
        int row = (tid >> 4) + jj * 16;
        int r2  = min(off + m0 + row, Tm1);
        float4 kv = *(const float4*)(tk + (size_t)r2 * STRIDE + h * DDIM + (tid & 15) * 4);
        uint2 pk;
        pk.x = pk2(kv.x, kv.y);
        pk.y = pk2(kv.z, kv.w);
        *(uint2*)&Ks[row * 64 + (((tid & 15) * 4) ^ ((row & 7) << 3))] = pk;
      }
      {
        uint bb[8];
#pragma unroll
        for (int j = 0; j < 8; ++j) {
          int ra = min(off + m0 + w * 16 + 2 * j,     Tm1);
          int rb = min(off + m0 + w * 16 + 2 * j + 1, Tm1);
          float va = tv[(size_t)ra * STRIDE + h * DDIM + lane];
          float vb = tv[(size_t)rb * STRIDE + h * DDIM + lane];
          bb[j] = pk2(va, vb);
        }
        int s = (lane & 7) << 3;
        *(uint4*)&Vt[lane * 64 + ((w * 16)     ^ s)] = make_uint4(bb[0], bb[1], bb[2], bb[3]);
        *(uint4*)&Vt[lane * 64 + ((w * 16 + 8) ^ s)] = make_uint4(bb[4], bb[5], bb[6], bb[7]);
      }
      __syncthreads();

#pragma unroll
      for (int kc = 0; kc < 4; ++kc) {
        const int krw = kc * 16 + lo;
        const int ksw = (krw & 7) << 3;
        short8 kf0 = *(const short8*)&Ks[krw * 64 + ((hi * 8) ^ ksw)];
        short8 kf1 = *(const short8*)&Ks[krw * 64 + ((32 + hi * 8) ^ ksw)];
        f32x4 s4 = (f32x4){0.f, 0.f, 0.f, 0.f};
        s4 = __builtin_amdgcn_mfma_f32_16x16x32_bf16(qf[0], kf0, s4, 0, 0, 0);
        s4 = __builtin_amdgcn_mfma_f32_16x16x32_bf16(qf[1], kf1, s4, 0, 0, 0);
        const int mm = m0 + kc * 16 + lo;
#pragma unroll
        for (int r = 0; r < 4; ++r) {
          const bool valid = nok[r] & ((mm < thr[r]) | (mm == n_r[r]));
          float s = valid ? s4[r] : 0.f;
          float pp = s * invN * __builtin_amdgcn_rcpf(1.f + __expf(-s));
          const int ql = hi * 4 + r;
          Pw[ql * 64 + ((kc * 16 + lo) ^ ((ql & 7) << 3))] = (ushort)pk2(pp, pp);
        }
      }

#pragma unroll
      for (int mc = 0; mc < 2; ++mc) {
        short8 pf = *(const short8*)&Pw[lo * 64 + ((mc * 32 + hi * 8) ^ ((lo & 7) << 3))];
#pragma unroll
        for (int dvc = 0; dvc < 4; ++dvc) {
          const int vrow = dvc * 16 + lo;
          short8 vf = *(const short8*)&Vt[vrow * 64 + ((mc * 32 + hi * 8) ^ ((vrow & 7) << 3))];
          oacc[dvc] = __builtin_amdgcn_mfma_f32_16x16x32_bf16(pf, vf, oacc[dvc], 0, 0, 0);
        }
      }
    }

#pragma unroll
    for (int dvc = 0; dvc < 4; ++dvc) {
#pragma unroll
      for (int r = 0; r < 4; ++r) {
        int n = n0 + w * 16 + hi * 4 + r;
        if (n < L)
          out[(size_t)(off + n) * STRIDE + h * DDIM + dvc * 16 + lo] = oacc[dvc][r];
      }
    }
  }
}

extern "C" void kernel_launch(void* const* d_in, const int* in_sizes, int n_in,
                              void* d_out, int out_size, void* d_ws, size_t ws_size,
                              hipStream_t stream) {
  const float* tq      = (const float*)d_in[0];
  const float* tk      = (const float*)d_in[1];
  const float* tv      = (const float*)d_in[2];
  const int*   offsets = (const int*)d_in[3];
  const int*   pN      = (const int*)d_in[4];
  const int*   ncand   = (const int*)d_in[5];
  const int*   nctx    = (const int*)d_in[6];
  float*       out     = (float*)d_out;

  const int B = in_sizes[3] - 1;
  const int T = in_sizes[0] / STRIDE;

  uint*   ctr   = (uint*)d_ws;
  short*  sched = (short*)((char*)d_ws + 256);
  ushort* tiles = (ushort*)((char*)d_ws + 256 + NBLK * SLOTS * sizeof(short));
  const size_t need = 256 + NBLK * SLOTS * sizeof(short)
                      + (size_t)B * NORD * HH * TILE_HW * sizeof(ushort);

  dim3 block(256);

  if (ws_size >= need && B <= 16) {
    dim3 tgrid(NORD, HH, B);
    build_tiles<<<tgrid, block, 0, stream>>>(tk, tv, tiles, offsets, ctr);
    make_sched<<<1, block, 0, stream>>>(offsets, B, sched);
    hstu_s<<<NBLK, block, 0, stream>>>(tq, tiles, sched, offsets, pN, ncand,
                                       nctx, out, T - 1);
  } else {
    zero_ctr<<<1, 1, 0, stream>>>(ctr);
    hstu_fb<<<NBLK, block, 0, stream>>>(tq, tk, tv, offsets, pN, ncand,
                                        nctx, out, ctr, T - 1, B);
  }
}

// Round 11
// 65.022 us; speedup vs baseline: 1.9668x; 1.1148x over previous
//
#include <hip/hip_runtime.h>
#include <math.h>

// HSTU jagged attention, MFMA bf16, DMA-staged, static XCD-affine LPT schedule.
// out = (silu(Q K^T) / N * mask) V, no softmax. H=8, D=DV=64, N=1024.
// Mask (exact collapse): valid(n,m) = (m < thr(n)) | (m == n),
//   thr(n) = (an>0 ? an : M) + c - 1, an = clamp(n-c+1,0,M), M = L-c+1-ncand.
// R11: (a) scheduler is atomics-free, folded into build_tiles block (0,0,0);
//      (b) swapped QK^T (mfma(K,Q)) -> lane holds P[q=lo][m=..4hi+r]:
//          packed ds_write_b64 P-writes (4 vs 16 b16), scalar per-lane mask.

#define HH      8
#define DDIM    64
#define QT      64
#define KT      64
#define STRIDE  512
#define NMAX    1024
#define NORD    16
#define TILE_HW 8192          // ushorts per tile image (16 KB)
#define NBLK    1024
#define SLOTS   8

typedef __attribute__((ext_vector_type(8))) short short8;
typedef __attribute__((ext_vector_type(4))) float f32x4;
typedef __attribute__((ext_vector_type(4))) uint  u32x4;

static __device__ __forceinline__ uint pk2(float a, float b) {
  uint r;
  asm("v_cvt_pk_bf16_f32 %0, %1, %2" : "=v"(r) : "v"(a), "v"(b));
  return r;
}

static __device__ __forceinline__ void dma16(const ushort* g, ushort* l) {
  __builtin_amdgcn_global_load_lds(
      (const __attribute__((address_space(1))) void*)g,
      (__attribute__((address_space(3))) void*)l, 16, 0, 0);
}

// ---- pre-pass: packed swizzled tile images [K 8KB | V^T 8KB].
//      Block (0,0,0) additionally emits the static LPT schedule (no atomics).
__global__ void build_tiles(const float* __restrict__ tk,
                            const float* __restrict__ tv,
                            ushort* __restrict__ tiles,
                            const int* __restrict__ offsets,
                            short* __restrict__ sched, int Bb) {
  const int mt = blockIdx.x, h = blockIdx.y, b = blockIdx.z;
  const int off = offsets[b];
  const int L   = offsets[b + 1] - off;
  const int tid = threadIdx.x;
  const bool sched_block = (mt == 0 && h == 0 && b == 0);

  if (mt * 64 < L) {
    ushort* img = tiles + (size_t)((b * NORD + mt) * HH + h) * TILE_HW;
    const int row = tid >> 2;
    const int c0  = (tid & 3) * 16;
    const int m   = mt * 64 + row;
    const int sw  = (row & 7) << 3;

    __shared__ ushort tr[64][66];

    {
      uint u[8];
      if (m < L) {
        const float* s = tk + (size_t)(off + m) * STRIDE + h * DDIM + c0;
        float4 a = *(const float4*)(s),      b4 = *(const float4*)(s + 4);
        float4 c4 = *(const float4*)(s + 8), d4 = *(const float4*)(s + 12);
        u[0] = pk2(a.x, a.y);   u[1] = pk2(a.z, a.w);
        u[2] = pk2(b4.x, b4.y); u[3] = pk2(b4.z, b4.w);
        u[4] = pk2(c4.x, c4.y); u[5] = pk2(c4.z, c4.w);
        u[6] = pk2(d4.x, d4.y); u[7] = pk2(d4.z, d4.w);
      } else {
#pragma unroll
        for (int j = 0; j < 8; ++j) u[j] = 0u;
      }
      *(uint4*)&img[row * 64 + (c0 ^ sw)]       = make_uint4(u[0], u[1], u[2], u[3]);
      *(uint4*)&img[row * 64 + ((c0 + 8) ^ sw)] = make_uint4(u[4], u[5], u[6], u[7]);
    }
    {
      uint u[8];
      if (m < L) {
        const float* s = tv + (size_t)(off + m) * STRIDE + h * DDIM + c0;
        float4 a = *(const float4*)(s),      b4 = *(const float4*)(s + 4);
        float4 c4 = *(const float4*)(s + 8), d4 = *(const float4*)(s + 12);
        u[0] = pk2(a.x, a.y);   u[1] = pk2(a.z, a.w);
        u[2] = pk2(b4.x, b4.y); u[3] = pk2(b4.z, b4.w);
        u[4] = pk2(c4.x, c4.y); u[5] = pk2(c4.z, c4.w);
        u[6] = pk2(d4.x, d4.y); u[7] = pk2(d4.z, d4.w);
      } else {
#pragma unroll
        for (int j = 0; j < 8; ++j) u[j] = 0u;
      }
#pragma unroll
      for (int j = 0; j < 8; ++j) *(uint*)&tr[row][c0 + 2 * j] = u[j];
    }
    __syncthreads();
    {
      uint u[8];
#pragma unroll
      for (int j = 0; j < 8; ++j)
        u[j] = (uint)tr[c0 + 2 * j][row] | ((uint)tr[c0 + 2 * j + 1][row] << 16);
      *(uint4*)&img[4096 + row * 64 + (c0 ^ sw)]       = make_uint4(u[0], u[1], u[2], u[3]);
      *(uint4*)&img[4096 + row * 64 + ((c0 + 8) ^ sw)] = make_uint4(u[4], u[5], u[6], u[7]);
    }
  }

  // ---- schedule (block (0,0,0) only): deterministic, atomics-free ----
  if (!sched_block) return;
  for (int i = tid; i < NBLK * SLOTS; i += 256) sched[i] = (short)-1;
  __syncthreads();
  if (tid < 64) {
    const int g = tid >> 3, hh = tid & 7;
    int nq[16];
    {
      int o0 = offsets[0];
      for (int bb = 0; bb < Bb; ++bb) {
        int o1 = offsets[bb + 1];
        nq[bb] = (o1 - o0 + QT - 1) / QT;
        o0 = o1;
      }
    }
    // rank batches by nq desc (stable); pair heavy r with light Bb-1-r -> grp r%8
    int gb0 = -1, gb1 = -1;
    for (int bb = 0; bb < Bb; ++bb) {
      int r = 0;
      for (int j = 0; j < Bb; ++j)
        r += (nq[j] > nq[bb]) || (nq[j] == nq[bb] && j < bb);
      int gg = (r < Bb / 2) ? (r & 7) : ((Bb - 1 - r) & 7);
      if (gg == g) { if (r < Bb / 2) gb0 = bb; else gb1 = bb; }
    }
    // enumerate group's items desc-cost; heads expand consecutively
    int i = 0;
    for (int cst = 16; cst >= 1; --cst) {
      for (int s = 0; s < 2; ++s) {
        int bb = (s == 0) ? gb0 : gb1;
        if (bb < 0) continue;
        const int q = nq[bb];
        // qt=0 (contextual full sweep) has cost q
        for (int which = 0; which < 2; ++which) {
          int qt = -1;
          if (which == 0 && cst == q) qt = 0;
          if (which == 1 && cst <= q && cst >= 2) qt = cst - 1;
          if (qt < 0) continue;
          const int rank = i * 8 + hh;
          const int pos  = rank & 255;
          const int lb   = (pos < 128) ? pos : 255 - pos;
          const int blk  = g + 8 * lb;                 // stays on XCD g
          const int slot = (pos < 128) ? 2 * (rank >> 8) : 2 * (rank >> 8) + 1;
          if (slot < SLOTS)
            sched[blk * SLOTS + slot] = (short)((bb << 7) | (hh << 4) | qt);
          ++i;
        }
      }
    }
  }
}

__global__ void zero_ctr(uint* ctr) { *ctr = 0u; }

// ---- main: DMA-staged, statically scheduled, swapped-QK packed-P ----
__launch_bounds__(256, 4)
__global__ void hstu_s(const float* __restrict__ tq,
                       const ushort* __restrict__ tiles,
                       const short* __restrict__ sched,
                       const int* __restrict__ offsets,
                       const int* __restrict__ pN,
                       const int* __restrict__ ncand,
                       const int* __restrict__ nctx,
                       float* __restrict__ out, int Tm1) {
  __shared__ ushort KV[2][TILE_HW];  // double-buffered [K 8KB | V^T 8KB]  32 KB
  __shared__ ushort Ps[4 * 1024];    // per-wave P strips                  8 KB

  const int tid  = threadIdx.x;
  const int w    = tid >> 6;
  const int lane = tid & 63;
  const int lo   = lane & 15;
  const int hi   = lane >> 4;

  const float invN = 1.0f / (float)pN[0];
  ushort* Pw = &Ps[w * 1024];
  const short* my = sched + blockIdx.x * SLOTS;

  for (int slot = 0; slot < SLOTS; ++slot) {
    const int e = my[slot];
    if (e < 0) return;
    const int b = (e >> 7) & 15, h = (e >> 4) & 7, qt = e & 15;
    const int off = offsets[b];
    const int L   = offsets[b + 1] - off;
    const int n0  = qt * QT;
    if (n0 >= L) continue;

    const int c = nctx[b];
    const int M = L - c + 1 - ncand[b];
    const int m_hi  = (n0 < c) ? L : min(n0 + QT, L);
    const int niter = (m_hi + KT - 1) / KT;

    const ushort* ibase = tiles + (size_t)(b * NORD * HH + h) * TILE_HW;

    __syncthreads();                         // prev item's LDS fully consumed

    // prologue: DMA tile 0 into KV[0]
    {
      const ushort* src = ibase + w * 2048 + lane * 8;
      ushort* dst = &KV[0][w * 2048];
#pragma unroll
      for (int i = 0; i < 4; ++i) dma16(src + i * 512, dst + i * 512);
    }

    // Q -> registers (frag: entity row = w*16+lo, k = ks*32 + hi*8 + 0..7)
    short8 qf[2];
    {
      int qr = min(off + n0 + w * 16 + lo, Tm1);
      const float* qp = tq + (size_t)qr * STRIDE + h * DDIM + hi * 8;
      float4 qa = *(const float4*)(qp);
      float4 qb = *(const float4*)(qp + 4);
      float4 qc = *(const float4*)(qp + 32);
      float4 qd = *(const float4*)(qp + 36);
      u32x4 v0 = {pk2(qa.x, qa.y), pk2(qa.z, qa.w), pk2(qb.x, qb.y), pk2(qb.z, qb.w)};
      u32x4 v1 = {pk2(qc.x, qc.y), pk2(qc.z, qc.w), pk2(qd.x, qd.y), pk2(qd.z, qd.w)};
      qf[0] = __builtin_bit_cast(short8, v0);
      qf[1] = __builtin_bit_cast(short8, v1);
    }

    // per-lane mask scalars (q-row = n): valid = nok & ((m < thr) | (m == n))
    const int  n   = n0 + w * 16 + lo;
    const int  an  = min(max(n - c + 1, 0), M);
    const int  thr = (an > 0 ? an : M) + c - 1;
    const bool nok = n < L;

    f32x4 oacc[4];
#pragma unroll
    for (int i = 0; i < 4; ++i) oacc[i] = (f32x4){0.f, 0.f, 0.f, 0.f};

    for (int t = 0; t < niter; ++t) {
      __syncthreads();   // drains tile-t DMA; gates buf (t+1)&1 reuse

      if (t + 1 < niter) {
        const ushort* src = ibase + (size_t)(t + 1) * (HH * TILE_HW)
                            + w * 2048 + lane * 8;
        ushort* dst = &KV[(t + 1) & 1][w * 2048];
#pragma unroll
        for (int i = 0; i < 4; ++i) dma16(src + i * 512, dst + i * 512);
      }

      const ushort* Kb = KV[t & 1];
      const ushort* Vb = Kb + 4096;
      const int m0 = t * KT;

      // S^T = K Q^T (swapped): lane holds P[q=lo][m = m0+kc*16+4*hi+r]
#pragma unroll
      for (int kc = 0; kc < 4; ++kc) {
        const int krw = kc * 16 + lo;
        const int ksw = (krw & 7) << 3;
        short8 kf0 = *(const short8*)&Kb[krw * 64 + ((hi * 8) ^ ksw)];
        short8 kf1 = *(const short8*)&Kb[krw * 64 + ((32 + hi * 8) ^ ksw)];
        f32x4 s4 = (f32x4){0.f, 0.f, 0.f, 0.f};
        s4 = __builtin_amdgcn_mfma_f32_16x16x32_bf16(kf0, qf[0], s4, 0, 0, 0);
        s4 = __builtin_amdgcn_mfma_f32_16x16x32_bf16(kf1, qf[1], s4, 0, 0, 0);
        const int mb = m0 + kc * 16 + 4 * hi;
        float pp[4];
#pragma unroll
        for (int r = 0; r < 4; ++r) {
          const int mm = mb + r;
          const bool valid = nok & ((mm < thr) | (mm == n));
          float s = valid ? s4[r] : 0.f;     // silu(0)=0; no NaN path
          pp[r] = s * invN * __builtin_amdgcn_rcpf(1.f + __expf(-s));
        }
        const int col = kc * 16 + 4 * hi;    // 4-aligned -> 8B packed write
        *(uint2*)&Pw[lo * 64 + (col ^ ((lo & 7) << 3))] =
            make_uint2(pk2(pp[0], pp[1]), pk2(pp[2], pp[3]));
      }

      // O += P V (wave-private P round-trip, no barrier)
#pragma unroll
      for (int mc = 0; mc < 2; ++mc) {
        short8 pf = *(const short8*)&Pw[lo * 64 + ((mc * 32 + hi * 8) ^ ((lo & 7) << 3))];
#pragma unroll
        for (int dvc = 0; dvc < 4; ++dvc) {
          const int vrow = dvc * 16 + lo;
          short8 vf = *(const short8*)&Vb[vrow * 64 + ((mc * 32 + hi * 8) ^ ((vrow & 7) << 3))];
          oacc[dvc] = __builtin_amdgcn_mfma_f32_16x16x32_bf16(pf, vf, oacc[dvc], 0, 0, 0);
        }
      }
    }

    // write out (fp32), C-frag layout: row q = 4*hi+r, col dv = dvc*16+lo
#pragma unroll
    for (int dvc = 0; dvc < 4; ++dvc) {
#pragma unroll
      for (int r = 0; r < 4; ++r) {
        int nn = n0 + w * 16 + hi * 4 + r;
        if (nn < L)
          out[(size_t)(off + nn) * STRIDE + h * DDIM + dvc * 16 + lo] = oacc[dvc][r];
      }
    }
  }
}

// ---- fallback (ws too small / B>16): reg-staged fp32 queue path ----
__launch_bounds__(256)
__global__ void hstu_fb(const float* __restrict__ tq,
                        const float* __restrict__ tk,
                        const float* __restrict__ tv,
                        const int* __restrict__ offsets,
                        const int* __restrict__ pN,
                        const int* __restrict__ ncand,
                        const int* __restrict__ nctx,
                        float* __restrict__ out,
                        uint* __restrict__ ctr,
                        int Tm1, int Bb) {
  const int bhc    = Bb * HH;
  const int nitems = NORD * bhc;

  __shared__ ushort Ks[KT * DDIM];
  __shared__ ushort Vt[DDIM * KT];
  __shared__ ushort Ps[4 * 1024];
  __shared__ int s_item;

  const int tid  = threadIdx.x;
  const int w    = tid >> 6;
  const int lane = tid & 63;
  const int lo   = lane & 15;
  const int hi   = lane >> 4;
  const float invN = 1.0f / (float)pN[0];
  ushort* Pw = &Ps[w * 1024];

  for (;;) {
    __syncthreads();
    if (tid == 0) s_item = (int)atomicAdd(ctr, 1u);
    __syncthreads();
    const int item = s_item;
    if (item >= nitems) return;
    const int ord = item / bhc;
    const int rem = item - ord * bhc;
    const int b = rem / HH, h = rem - b * HH;
    const int qt = (ord == 0) ? 0 : (NORD - ord);
    const int off = offsets[b];
    const int L   = offsets[b + 1] - off;
    const int n0  = qt * QT;
    if (n0 >= L) continue;

    const int c = nctx[b];
    const int M = L - c + 1 - ncand[b];
    const int m_hi  = (n0 < c) ? L : min(n0 + QT, L);
    const int niter = (m_hi + KT - 1) / KT;

    short8 qf[2];
    {
      int qr = min(off + n0 + w * 16 + lo, Tm1);
      const float* qp = tq + (size_t)qr * STRIDE + h * DDIM + hi * 8;
      float4 qa = *(const float4*)(qp);
      float4 qb = *(const float4*)(qp + 4);
      float4 qc = *(const float4*)(qp + 32);
      float4 qd = *(const float4*)(qp + 36);
      u32x4 v0 = {pk2(qa.x, qa.y), pk2(qa.z, qa.w), pk2(qb.x, qb.y), pk2(qb.z, qb.w)};
      u32x4 v1 = {pk2(qc.x, qc.y), pk2(qc.z, qc.w), pk2(qd.x, qd.y), pk2(qd.z, qd.w)};
      qf[0] = __builtin_bit_cast(short8, v0);
      qf[1] = __builtin_bit_cast(short8, v1);
    }

    const int  n   = n0 + w * 16 + lo;
    const int  an  = min(max(n - c + 1, 0), M);
    const int  thr = (an > 0 ? an : M) + c - 1;
    const bool nok = n < L;

    f32x4 oacc[4];
#pragma unroll
    for (int i = 0; i < 4; ++i) oacc[i] = (f32x4){0.f, 0.f, 0.f, 0.f};

    for (int t = 0; t < niter; ++t) {
      const int m0 = t * KT;
      __syncthreads();
#pragma unroll
      for (int jj = 0; jj < 4; ++jj) {
        int row = (tid >> 4) + jj * 16;
        int r2  = min(off + m0 + row, Tm1);
        float4 kv = *(const float4*)(tk + (size_t)r2 * STRIDE + h * DDIM + (tid & 15) * 4);
        uint2 pk;
        pk.x = pk2(kv.x, kv.y);
        pk.y = pk2(kv.z, kv.w);
        *(uint2*)&Ks[row * 64 + (((tid & 15) * 4) ^ ((row & 7) << 3))] = pk;
      }
      {
        uint bb[8];
#pragma unroll
        for (int j = 0; j < 8; ++j) {
          int ra = min(off + m0 + w * 16 + 2 * j,     Tm1);
          int rb = min(off + m0 + w * 16 + 2 * j + 1, Tm1);
          float va = tv[(size_t)ra * STRIDE + h * DDIM + lane];
          float vb = tv[(size_t)rb * STRIDE + h * DDIM + lane];
          bb[j] = pk2(va, vb);
        }
        int s = (lane & 7) << 3;
        *(uint4*)&Vt[lane * 64 + ((w * 16)     ^ s)] = make_uint4(bb[0], bb[1], bb[2], bb[3]);
        *(uint4*)&Vt[lane * 64 + ((w * 16 + 8) ^ s)] = make_uint4(bb[4], bb[5], bb[6], bb[7]);
      }
      __syncthreads();

#pragma unroll
      for (int kc = 0; kc < 4; ++kc) {
        const int krw = kc * 16 + lo;
        const int ksw = (krw & 7) << 3;
        short8 kf0 = *(const short8*)&Ks[krw * 64 + ((hi * 8) ^ ksw)];
        short8 kf1 = *(const short8*)&Ks[krw * 64 + ((32 + hi * 8) ^ ksw)];
        f32x4 s4 = (f32x4){0.f, 0.f, 0.f, 0.f};
        s4 = __builtin_amdgcn_mfma_f32_16x16x32_bf16(kf0, qf[0], s4, 0, 0, 0);
        s4 = __builtin_amdgcn_mfma_f32_16x16x32_bf16(kf1, qf[1], s4, 0, 0, 0);
        const int mb = m0 + kc * 16 + 4 * hi;
        float pp[4];
#pragma unroll
        for (int r = 0; r < 4; ++r) {
          const int mm = mb + r;
          const bool valid = nok & ((mm < thr) | (mm == n));
          float s = valid ? s4[r] : 0.f;
          pp[r] = s * invN * __builtin_amdgcn_rcpf(1.f + __expf(-s));
        }
        const int col = kc * 16 + 4 * hi;
        *(uint2*)&Pw[lo * 64 + (col ^ ((lo & 7) << 3))] =
            make_uint2(pk2(pp[0], pp[1]), pk2(pp[2], pp[3]));
      }

#pragma unroll
      for (int mc = 0; mc < 2; ++mc) {
        short8 pf = *(const short8*)&Pw[lo * 64 + ((mc * 32 + hi * 8) ^ ((lo & 7) << 3))];
#pragma unroll
        for (int dvc = 0; dvc < 4; ++dvc) {
          const int vrow = dvc * 16 + lo;
          short8 vf = *(const short8*)&Vt[vrow * 64 + ((mc * 32 + hi * 8) ^ ((vrow & 7) << 3))];
          oacc[dvc] = __builtin_amdgcn_mfma_f32_16x16x32_bf16(pf, vf, oacc[dvc], 0, 0, 0);
        }
      }
    }

#pragma unroll
    for (int dvc = 0; dvc < 4; ++dvc) {
#pragma unroll
      for (int r = 0; r < 4; ++r) {
        int nn = n0 + w * 16 + hi * 4 + r;
        if (nn < L)
          out[(size_t)(off + nn) * STRIDE + h * DDIM + dvc * 16 + lo] = oacc[dvc][r];
      }
    }
  }
}

extern "C" void kernel_launch(void* const* d_in, const int* in_sizes, int n_in,
                              void* d_out, int out_size, void* d_ws, size_t ws_size,
                              hipStream_t stream) {
  const float* tq      = (const float*)d_in[0];
  const float* tk      = (const float*)d_in[1];
  const float* tv      = (const float*)d_in[2];
  const int*   offsets = (const int*)d_in[3];
  const int*   pN      = (const int*)d_in[4];
  const int*   ncand   = (const int*)d_in[5];
  const int*   nctx    = (const int*)d_in[6];
  float*       out     = (float*)d_out;

  const int B = in_sizes[3] - 1;
  const int T = in_sizes[0] / STRIDE;

  uint*   ctr   = (uint*)d_ws;
  short*  sched = (short*)((char*)d_ws + 256);
  ushort* tiles = (ushort*)((char*)d_ws + 256 + NBLK * SLOTS * sizeof(short));
  const size_t need = 256 + NBLK * SLOTS * sizeof(short)
                      + (size_t)B * NORD * HH * TILE_HW * sizeof(ushort);

  dim3 block(256);

  if (ws_size >= need && B <= 16) {
    dim3 tgrid(NORD, HH, B);
    build_tiles<<<tgrid, block, 0, stream>>>(tk, tv, tiles, offsets, sched, B);
    hstu_s<<<NBLK, block, 0, stream>>>(tq, tiles, sched, offsets, pN, ncand,
                                       nctx, out, T - 1);
  } else {
    zero_ctr<<<1, 1, 0, stream>>>(ctr);
    hstu_fb<<<NBLK, block, 0, stream>>>(tq, tk, tv, offsets, pN, ncand,
                                        nctx, out, ctr, T - 1, B);
  }
}